// Round 3
// baseline (823.961 us; speedup 1.0000x reference)
//
#include <hip/hip_runtime.h>
#include <hip/hip_bf16.h>
#include <math.h>

#define N_NODES 20000
#define N_EDGES 320000
#define IN_DIM 128
#define HID 256
#define HEADS 8
#define DH 32
#define LAYERS 3
#define NUM_GRAPHS 64
#define OUT_DIM 10
#define SLOPE 0.2f

// ---------------- utility kernels ----------------
__global__ void zero_kernel(float* __restrict__ p, int n) {
    int i = blockIdx.x * blockDim.x + threadIdx.x;
    if (i < n) p[i] = 0.f;
}

// ---------------- CSR build (group edges by dst) ----------------
__global__ void count_kernel(const int* __restrict__ dst, int* __restrict__ cnt) {
    int e = blockIdx.x * blockDim.x + threadIdx.x;
    if (e < N_EDGES) atomicAdd(&cnt[dst[e]], 1);
}

__global__ __launch_bounds__(256) void scan_kernel(const int* __restrict__ cnt,
                                                   int* __restrict__ offs,
                                                   int* __restrict__ cursor) {
    __shared__ int part[256];
    int t = threadIdx.x;
    const int chunk = (N_NODES + 255) / 256;  // 79
    int beg = t * chunk;
    int end = beg + chunk; if (end > N_NODES) end = N_NODES;
    int s = 0;
    for (int i = beg; i < end; ++i) s += cnt[i];
    part[t] = s;
    __syncthreads();
    if (t == 0) {
        int run = 0;
        for (int i = 0; i < 256; ++i) { int v = part[i]; part[i] = run; run += v; }
        offs[N_NODES] = run;
    }
    __syncthreads();
    int run = part[t];
    for (int i = beg; i < end; ++i) {
        offs[i] = run; cursor[i] = run; run += cnt[i];
    }
}

__global__ void fill_kernel(const int* __restrict__ src, const int* __restrict__ dst,
                            int* __restrict__ cursor, int* __restrict__ csr_src) {
    int e = blockIdx.x * blockDim.x + threadIdx.x;
    if (e < N_EDGES) {
        int p = atomicAdd(&cursor[dst[e]], 1);
        csr_src[p] = src[e];
    }
}

// ---------------- fast fp32 GEMM, optionally dual-B ----------------
// C1[M,N] = A[M,K] @ B1[K,N] + bias1 ; if DUAL also C2 = A @ B2 + bias2.
// 128(M) x 64(N) block tile, 256 threads, 8x4 micro-tile per thread (per output).
// A staged k-major (transposed) into LDS so inner-loop A reads are broadcast
// across the 16 tx lanes and conflict-free across ty.
template <int DUAL>
__global__ __launch_bounds__(256) void gemm_fast(
    const float* __restrict__ A,
    const float* __restrict__ B1, const float* __restrict__ bias1, float* __restrict__ C1,
    const float* __restrict__ B2, const float* __restrict__ bias2, float* __restrict__ C2,
    int M, int K, int N) {
    __shared__ float As[16][129];   // [k][m], +1 pad breaks staging-store conflicts
    __shared__ float Bs1[16][64];   // [k][n]
    __shared__ float Bs2[DUAL ? 16 : 1][DUAL ? 64 : 1];

    int t = threadIdx.x;
    int tx = t & 15;      // n-group: cols tx*4 .. tx*4+3
    int ty = t >> 4;      // m-group: rows ty + 16*i, i=0..7 (interleaved)
    int m0 = blockIdx.x * 128, n0 = blockIdx.y * 64;

    float acc1[8][4] = {};
    float acc2[8][4] = {};

    for (int k0 = 0; k0 < K; k0 += 16) {
        // stage A: 128 rows x 16 k = 512 float4, 2 per thread, transposed
#pragma unroll
        for (int i = 0; i < 2; ++i) {
            int g = t + i * 256;
            int row = g >> 2;            // 0..127
            int kc = (g & 3) * 4;        // 0,4,8,12
            int gm = m0 + row;
            float4 av = make_float4(0.f, 0.f, 0.f, 0.f);
            if (gm < M) av = *(const float4*)(A + (size_t)gm * K + k0 + kc);
            As[kc + 0][row] = av.x;
            As[kc + 1][row] = av.y;
            As[kc + 2][row] = av.z;
            As[kc + 3][row] = av.w;
        }
        // stage B tiles: 16 k x 64 n = 256 float4, 1 per thread (per B)
        {
            int kr = t >> 4;             // 0..15
            int nc = (t & 15) * 4;       // 0..60
            *(float4*)&Bs1[kr][nc] = *(const float4*)(B1 + (size_t)(k0 + kr) * N + n0 + nc);
            if (DUAL)
                *(float4*)&Bs2[kr][nc] = *(const float4*)(B2 + (size_t)(k0 + kr) * N + n0 + nc);
        }
        __syncthreads();
#pragma unroll
        for (int k = 0; k < 16; ++k) {
            float a[8];
#pragma unroll
            for (int i = 0; i < 8; ++i) a[i] = As[k][ty + 16 * i];
            float4 bv1 = *(const float4*)&Bs1[k][tx * 4];
#pragma unroll
            for (int i = 0; i < 8; ++i) {
                acc1[i][0] += a[i] * bv1.x;
                acc1[i][1] += a[i] * bv1.y;
                acc1[i][2] += a[i] * bv1.z;
                acc1[i][3] += a[i] * bv1.w;
            }
            if (DUAL) {
                float4 bv2 = *(const float4*)&Bs2[k][tx * 4];
#pragma unroll
                for (int i = 0; i < 8; ++i) {
                    acc2[i][0] += a[i] * bv2.x;
                    acc2[i][1] += a[i] * bv2.y;
                    acc2[i][2] += a[i] * bv2.z;
                    acc2[i][3] += a[i] * bv2.w;
                }
            }
        }
        __syncthreads();
    }

    float4 bb1 = *(const float4*)(bias1 + n0 + tx * 4);
    float4 bb2 = make_float4(0.f, 0.f, 0.f, 0.f);
    if (DUAL) bb2 = *(const float4*)(bias2 + n0 + tx * 4);
#pragma unroll
    for (int i = 0; i < 8; ++i) {
        int gm = m0 + ty + 16 * i;
        if (gm < M) {
            int gn = n0 + tx * 4;
            float4 o1;
            o1.x = acc1[i][0] + bb1.x; o1.y = acc1[i][1] + bb1.y;
            o1.z = acc1[i][2] + bb1.z; o1.w = acc1[i][3] + bb1.w;
            *(float4*)(C1 + (size_t)gm * N + gn) = o1;
            if (DUAL) {
                float4 o2;
                o2.x = acc2[i][0] + bb2.x; o2.y = acc2[i][1] + bb2.y;
                o2.z = acc2[i][2] + bb2.z; o2.w = acc2[i][3] + bb2.w;
                *(float4*)(C2 + (size_t)gm * N + gn) = o2;
            }
        }
    }
}

// ---------------- GATv2 aggregation: one wave per node, online softmax ----------------
// lane l covers feature dims l*4..l*4+3 ; head = l>>3 ; head-local dims (l&7)*4..
__global__ __launch_bounds__(256) void gat_agg_kernel(
    const float* __restrict__ fs, const float* __restrict__ fd,
    float* __restrict__ h, const int* __restrict__ offs,
    const int* __restrict__ csr_src, const float* __restrict__ attn_l) {
    int gw = (blockIdx.x * blockDim.x + threadIdx.x) >> 6;
    if (gw >= N_NODES) return;
    int lane = threadIdx.x & 63;
    int node = gw;

    int abase = (lane >> 3) * DH + (lane & 7) * 4;
    float4 av = *(const float4*)(attn_l + abase);
    float a0 = av.x, a1 = av.y, a2 = av.z, a3 = av.w;

    float4 fdv = *(const float4*)(fd + (size_t)node * HID + lane * 4);

    int beg = offs[node], end = offs[node + 1];
    float m = -INFINITY, ssum = 0.f;
    float acc0 = 0.f, acc1 = 0.f, acc2 = 0.f, acc3 = 0.f;

    for (int idx = beg; idx < end; ++idx) {
        int sv = csr_src[idx];
        float4 fsv = *(const float4*)(fs + (size_t)sv * HID + lane * 4);
        float e0 = fsv.x + fdv.x; e0 = e0 > 0.f ? e0 : SLOPE * e0;
        float e1 = fsv.y + fdv.y; e1 = e1 > 0.f ? e1 : SLOPE * e1;
        float e2 = fsv.z + fdv.z; e2 = e2 > 0.f ? e2 : SLOPE * e2;
        float e3 = fsv.w + fdv.w; e3 = e3 > 0.f ? e3 : SLOPE * e3;
        float p = e0 * a0 + e1 * a1 + e2 * a2 + e3 * a3;
        // reduce over the 8 lanes of this head (aligned groups -> xor stays in group)
        p += __shfl_xor(p, 1, 64);
        p += __shfl_xor(p, 2, 64);
        p += __shfl_xor(p, 4, 64);
        float mn = fmaxf(m, p);
        float corr = __expf(m - mn);   // m=-inf first iter -> corr=0
        float w = __expf(p - mn);
        ssum = ssum * corr + w;
        acc0 = acc0 * corr + w * fsv.x;
        acc1 = acc1 * corr + w * fsv.y;
        acc2 = acc2 * corr + w * fsv.z;
        acc3 = acc3 * corr + w * fsv.w;
        m = mn;
    }

    float inv = ssum > 0.f ? 1.f / ssum : 0.f;
    float4 hv = *(const float4*)(h + (size_t)node * HID + lane * 4);
    float4 o;
    o.x = fmaxf(acc0 * inv + hv.x, 0.f);
    o.y = fmaxf(acc1 * inv + hv.y, 0.f);
    o.z = fmaxf(acc2 * inv + hv.z, 0.f);
    o.w = fmaxf(acc3 * inv + hv.w, 0.f);
    *(float4*)(h + (size_t)node * HID + lane * 4) = o;
}

// ---------------- graph sum-pool (graph_ids sorted -> run-length local acc) ----------------
#define POOL_CHUNK 32
__global__ __launch_bounds__(64) void pool_kernel(const float* __restrict__ h,
                                                  const int* __restrict__ gid,
                                                  float* __restrict__ hg) {
    int t = threadIdx.x;
    int n0 = blockIdx.x * POOL_CHUNK;
    int n1 = n0 + POOL_CHUNK; if (n1 > N_NODES) n1 = N_NODES;
    if (n0 >= N_NODES) return;
    float4 acc = make_float4(0.f, 0.f, 0.f, 0.f);
    int cur = gid[n0];
    for (int n = n0; n < n1; ++n) {
        int g = gid[n];
        if (g != cur) {
            atomicAdd(&hg[(size_t)cur * HID + t * 4 + 0], acc.x);
            atomicAdd(&hg[(size_t)cur * HID + t * 4 + 1], acc.y);
            atomicAdd(&hg[(size_t)cur * HID + t * 4 + 2], acc.z);
            atomicAdd(&hg[(size_t)cur * HID + t * 4 + 3], acc.w);
            acc = make_float4(0.f, 0.f, 0.f, 0.f);
            cur = g;
        }
        float4 v = *(const float4*)(h + (size_t)n * HID + t * 4);
        acc.x += v.x; acc.y += v.y; acc.z += v.z; acc.w += v.w;
    }
    atomicAdd(&hg[(size_t)cur * HID + t * 4 + 0], acc.x);
    atomicAdd(&hg[(size_t)cur * HID + t * 4 + 1], acc.y);
    atomicAdd(&hg[(size_t)cur * HID + t * 4 + 2], acc.z);
    atomicAdd(&hg[(size_t)cur * HID + t * 4 + 3], acc.w);
}

// ---------------- classifier: one block per graph ----------------
__global__ __launch_bounds__(256) void classifier_kernel(
    const float* __restrict__ hg,
    const float* __restrict__ Wc1, const float* __restrict__ bc1,
    const float* __restrict__ Wc2, const float* __restrict__ bc2,
    const float* __restrict__ Wc3, const float* __restrict__ bc3,
    float* __restrict__ out) {
    __shared__ float xin[HID];
    __shared__ float x1[HID];
    __shared__ float x2[HID / 2];
    int g = blockIdx.x, t = threadIdx.x;
    xin[t] = hg[(size_t)g * HID + t];
    __syncthreads();
    {
        float acc = bc1[t];
        for (int k = 0; k < HID; ++k) acc += xin[k] * Wc1[k * HID + t];
        x1[t] = fmaxf(acc, 0.f);
    }
    __syncthreads();
    if (t < HID / 2) {
        float acc = bc2[t];
        for (int k = 0; k < HID; ++k) acc += x1[k] * Wc2[k * (HID / 2) + t];
        x2[t] = fmaxf(acc, 0.f);
    }
    __syncthreads();
    if (t < OUT_DIM) {
        float acc = bc3[t];
        for (int k = 0; k < HID / 2; ++k) acc += x2[k] * Wc3[k * OUT_DIM + t];
        out[g * OUT_DIM + t] = acc;
    }
}

// ---------------- launch ----------------
extern "C" void kernel_launch(void* const* d_in, const int* in_sizes, int n_in,
                              void* d_out, int out_size, void* d_ws, size_t ws_size,
                              hipStream_t stream) {
    const float* feature = (const float*)d_in[0];
    const float* W_in   = (const float*)d_in[1];
    const float* b_in   = (const float*)d_in[2];
    const float* W_src  = (const float*)d_in[3];
    const float* b_src  = (const float*)d_in[4];
    const float* W_dst  = (const float*)d_in[5];
    const float* b_dst  = (const float*)d_in[6];
    const float* attn   = (const float*)d_in[7];
    const float* Wc1    = (const float*)d_in[8];
    const float* bc1    = (const float*)d_in[9];
    const float* Wc2    = (const float*)d_in[10];
    const float* bc2    = (const float*)d_in[11];
    const float* Wc3    = (const float*)d_in[12];
    const float* bc3    = (const float*)d_in[13];
    const int* src     = (const int*)d_in[14];
    const int* dst     = (const int*)d_in[15];
    const int* gid     = (const int*)d_in[16];
    float* out = (float*)d_out;

    char* w = (char*)d_ws;
    auto alloc = [&](size_t bytes) -> void* {
        void* p = (void*)w;
        w += (bytes + 255) & ~(size_t)255;
        return p;
    };
    float* h     = (float*)alloc((size_t)N_NODES * HID * 4);
    float* fs    = (float*)alloc((size_t)N_NODES * HID * 4);
    float* fd    = (float*)alloc((size_t)N_NODES * HID * 4);
    float* hg    = (float*)alloc((size_t)NUM_GRAPHS * HID * 4);
    int* cnt     = (int*)alloc((size_t)N_NODES * 4);
    int* offs    = (int*)alloc((size_t)(N_NODES + 1) * 4);
    int* cursor  = (int*)alloc((size_t)N_NODES * 4);
    int* csr_src = (int*)alloc((size_t)N_EDGES * 4);

    // init
    hipLaunchKernelGGL(zero_kernel, dim3((N_NODES + 255) / 256), dim3(256), 0, stream,
                       (float*)cnt, N_NODES);
    hipLaunchKernelGGL(zero_kernel, dim3((NUM_GRAPHS * HID + 255) / 256), dim3(256), 0, stream,
                       hg, NUM_GRAPHS * HID);

    // CSR build by dst
    hipLaunchKernelGGL(count_kernel, dim3((N_EDGES + 255) / 256), dim3(256), 0, stream, dst, cnt);
    hipLaunchKernelGGL(scan_kernel, dim3(1), dim3(256), 0, stream, cnt, offs, cursor);
    hipLaunchKernelGGL(fill_kernel, dim3((N_EDGES + 255) / 256), dim3(256), 0, stream,
                       src, dst, cursor, csr_src);

    dim3 ggrid((N_NODES + 127) / 128, HID / 64);  // 157 x 4

    // input projection: h = feature @ W_in + b_in
    hipLaunchKernelGGL((gemm_fast<0>), ggrid, dim3(256), 0, stream,
                       feature, W_in, b_in, h,
                       (const float*)nullptr, (const float*)nullptr, (float*)nullptr,
                       N_NODES, IN_DIM, HID);

    // GATv2 layers
    for (int l = 0; l < LAYERS; ++l) {
        hipLaunchKernelGGL((gemm_fast<1>), ggrid, dim3(256), 0, stream,
                           h,
                           W_src + (size_t)l * HID * HID, b_src + (size_t)l * HID, fs,
                           W_dst + (size_t)l * HID * HID, b_dst + (size_t)l * HID, fd,
                           N_NODES, HID, HID);
        hipLaunchKernelGGL(gat_agg_kernel, dim3((N_NODES * 64 + 255) / 256), dim3(256), 0, stream,
                           fs, fd, h, offs, csr_src, attn + (size_t)l * HEADS * DH);
    }

    // pool + classifier
    hipLaunchKernelGGL(pool_kernel, dim3((N_NODES + POOL_CHUNK - 1) / POOL_CHUNK), dim3(64), 0, stream,
                       h, gid, hg);
    hipLaunchKernelGGL(classifier_kernel, dim3(NUM_GRAPHS), dim3(256), 0, stream,
                       hg, Wc1, bc1, Wc2, bc2, Wc3, bc3, out);
}

// Round 4
// 488.781 us; speedup vs baseline: 1.6857x; 1.6857x over previous
//
#include <hip/hip_runtime.h>
#include <hip/hip_bf16.h>
#include <math.h>

#define N_NODES 20000
#define N_EDGES 320000
#define IN_DIM 128
#define HID 256
#define HEADS 8
#define DH 32
#define LAYERS 3
#define NUM_GRAPHS 64
#define OUT_DIM 10
#define SLOPE 0.2f

typedef __bf16 bf16x8 __attribute__((ext_vector_type(8)));
typedef float f32x4 __attribute__((ext_vector_type(4)));

static __device__ __forceinline__ unsigned short f2bfbits(float v) {
    __bf16 b = (__bf16)v;
    return __builtin_bit_cast(unsigned short, b);
}
static __device__ __forceinline__ float bfhival(float v) {
    __bf16 b = (__bf16)v;
    return (float)b;
}

// ---------------- utility kernels ----------------
__global__ void zero_kernel(float* __restrict__ p, int n) {
    int i = blockIdx.x * blockDim.x + threadIdx.x;
    if (i < n) p[i] = 0.f;
}

// feature fp32 (bf16-exact values) -> bf16 bits, 4 at a time
__global__ void cast4_kernel(const float* __restrict__ in, unsigned short* __restrict__ out, int n4) {
    int i = blockIdx.x * blockDim.x + threadIdx.x;
    if (i < n4) {
        float4 v = ((const float4*)in)[i];
        ushort4 o;
        o.x = f2bfbits(v.x); o.y = f2bfbits(v.y);
        o.z = f2bfbits(v.z); o.w = f2bfbits(v.w);
        ((ushort4*)out)[i] = o;
    }
}

// W_in [K=128][N=256] fp32 -> WinT [N][K] bf16 bits
__global__ void wtransK_kernel(const float* __restrict__ in, unsigned short* __restrict__ out,
                               int K, int N) {
    int idx = blockIdx.x * blockDim.x + threadIdx.x;
    if (idx < K * N) {
        int n = idx / K, k = idx % K;
        out[idx] = f2bfbits(in[k * N + n]);
    }
}

// 6 matrices (3 x W_src, 3 x W_dst), each [256][256] -> out [mat][n][k] bf16 bits
__global__ void wtrans6_kernel(const float* __restrict__ Wsrc, const float* __restrict__ Wdst,
                               unsigned short* __restrict__ out) {
    int idx = blockIdx.x * blockDim.x + threadIdx.x;
    if (idx < 6 * 65536) {
        int mat = idx >> 16;
        int r = idx & 65535;
        int n = r >> 8, k = r & 255;
        const float* base = (mat < 3) ? (Wsrc + (size_t)mat * 65536)
                                      : (Wdst + (size_t)(mat - 3) * 65536);
        out[idx] = f2bfbits(base[k * 256 + n]);
    }
}

// ---------------- CSR build (group edges by dst) ----------------
__global__ void count_kernel(const int* __restrict__ dst, int* __restrict__ cnt) {
    int e = blockIdx.x * blockDim.x + threadIdx.x;
    if (e < N_EDGES) atomicAdd(&cnt[dst[e]], 1);
}

__global__ __launch_bounds__(256) void scan_kernel(const int* __restrict__ cnt,
                                                   int* __restrict__ offs,
                                                   int* __restrict__ cursor) {
    __shared__ int part[256];
    int t = threadIdx.x;
    const int chunk = (N_NODES + 255) / 256;  // 79
    int beg = t * chunk;
    int end = beg + chunk; if (end > N_NODES) end = N_NODES;
    int s = 0;
    for (int i = beg; i < end; ++i) s += cnt[i];
    part[t] = s;
    __syncthreads();
    if (t == 0) {
        int run = 0;
        for (int i = 0; i < 256; ++i) { int v = part[i]; part[i] = run; run += v; }
        offs[N_NODES] = run;
    }
    __syncthreads();
    int run = part[t];
    for (int i = beg; i < end; ++i) {
        offs[i] = run; cursor[i] = run; run += cnt[i];
    }
}

__global__ void fill_kernel(const int* __restrict__ src, const int* __restrict__ dst,
                            int* __restrict__ cursor, int* __restrict__ csr_src) {
    int e = blockIdx.x * blockDim.x + threadIdx.x;
    if (e < N_EDGES) {
        int p = atomicAdd(&cursor[dst[e]], 1);
        csr_src[p] = src[e];
    }
}

// ---------------- MFMA GEMM ----------------
// C1[M,N] = (A_hi + A_lo)[M,K] @ B1[K,N] + bias1, B given TRANSPOSED as BT[n][k] bf16.
// DUAL: also C2 with BT2/bias2 sharing A. OUTSPLIT: also emit bf16 hi/lo of C1.
// Block tile 128(M) x 64(N), 4 waves; wave w covers rows w*32..w*32+31 via two
// 16-row MFMA tiles; 4 n-tiles of 16. mfma_f32_16x16x32_bf16:
//   A frag: m=lane&15, k=(lane>>4)*8+j ; B frag: n=lane&15, k=(lane>>4)*8+j
//   C/D:    col=lane&15, row=(lane>>4)*4+reg      (learn_hip m89/m91 verified)
// LDS rows padded to 40 bf16 (80 B) -> conflict-free ds_read_b128 fragments.
template <int SPLITA, int DUAL, int OUTSPLIT>
__global__ __launch_bounds__(256) void mfma_gemm(
    const unsigned short* __restrict__ Ah, const unsigned short* __restrict__ Al,
    const unsigned short* __restrict__ BT1, const float* __restrict__ bias1,
    float* __restrict__ C1,
    const unsigned short* __restrict__ BT2, const float* __restrict__ bias2,
    float* __restrict__ C2,
    unsigned short* __restrict__ Oh, unsigned short* __restrict__ Ol,
    int M, int K, int N) {
    __shared__ unsigned short As_hi[128 * 40];
    __shared__ unsigned short As_lo[SPLITA ? 128 * 40 : 8];
    __shared__ unsigned short Bs1[64 * 40];
    __shared__ unsigned short Bs2[DUAL ? 64 * 40 : 8];

    const int t = threadIdx.x;
    const int wv = t >> 6, lane = t & 63, quad = lane >> 4, l15 = lane & 15;
    const int m0 = blockIdx.x * 128, n0 = blockIdx.y * 64;

    f32x4 zero = {0.f, 0.f, 0.f, 0.f};
    f32x4 acc1[2][4], acc2[2][4];
#pragma unroll
    for (int mi = 0; mi < 2; ++mi)
#pragma unroll
        for (int t4 = 0; t4 < 4; ++t4) { acc1[mi][t4] = zero; acc2[mi][t4] = zero; }

    for (int k0 = 0; k0 < K; k0 += 32) {
        __syncthreads();
        // stage A tiles: 128 rows x 32 k, 16B per thread x2
#pragma unroll
        for (int i = 0; i < 2; ++i) {
            int g = t + i * 256;
            int r = g >> 2, s = g & 3;
            int gm = m0 + r;
            uint4 v = make_uint4(0u, 0u, 0u, 0u);
            if (gm < M) v = *(const uint4*)(Ah + (size_t)gm * K + k0 + s * 8);
            *(uint4*)(As_hi + r * 40 + s * 8) = v;
            if (SPLITA) {
                uint4 v2 = make_uint4(0u, 0u, 0u, 0u);
                if (gm < M) v2 = *(const uint4*)(Al + (size_t)gm * K + k0 + s * 8);
                *(uint4*)(As_lo + r * 40 + s * 8) = v2;
            }
        }
        // stage B tiles: 64 n-rows x 32 k from BT[n][k]
        {
            int r = t >> 2, s = t & 3;
            int gn = n0 + r;
            *(uint4*)(Bs1 + r * 40 + s * 8) = *(const uint4*)(BT1 + (size_t)gn * K + k0 + s * 8);
            if (DUAL)
                *(uint4*)(Bs2 + r * 40 + s * 8) = *(const uint4*)(BT2 + (size_t)gn * K + k0 + s * 8);
        }
        __syncthreads();

        bf16x8 aHi[2], aLo[2];
#pragma unroll
        for (int mi = 0; mi < 2; ++mi) {
            int row = wv * 32 + mi * 16 + l15;
            aHi[mi] = __builtin_bit_cast(bf16x8, *(const uint4*)(As_hi + row * 40 + quad * 8));
            if (SPLITA)
                aLo[mi] = __builtin_bit_cast(bf16x8, *(const uint4*)(As_lo + row * 40 + quad * 8));
        }
#pragma unroll
        for (int t4 = 0; t4 < 4; ++t4) {
            int brow = t4 * 16 + l15;
            bf16x8 b1 = __builtin_bit_cast(bf16x8, *(const uint4*)(Bs1 + brow * 40 + quad * 8));
#pragma unroll
            for (int mi = 0; mi < 2; ++mi) {
                acc1[mi][t4] = __builtin_amdgcn_mfma_f32_16x16x32_bf16(aHi[mi], b1, acc1[mi][t4], 0, 0, 0);
                if (SPLITA)
                    acc1[mi][t4] = __builtin_amdgcn_mfma_f32_16x16x32_bf16(aLo[mi], b1, acc1[mi][t4], 0, 0, 0);
            }
            if (DUAL) {
                bf16x8 b2 = __builtin_bit_cast(bf16x8, *(const uint4*)(Bs2 + brow * 40 + quad * 8));
#pragma unroll
                for (int mi = 0; mi < 2; ++mi) {
                    acc2[mi][t4] = __builtin_amdgcn_mfma_f32_16x16x32_bf16(aHi[mi], b2, acc2[mi][t4], 0, 0, 0);
                    if (SPLITA)
                        acc2[mi][t4] = __builtin_amdgcn_mfma_f32_16x16x32_bf16(aLo[mi], b2, acc2[mi][t4], 0, 0, 0);
                }
            }
        }
    }

    // epilogue
    float bia1[4], bia2[4];
#pragma unroll
    for (int t4 = 0; t4 < 4; ++t4) {
        bia1[t4] = bias1[n0 + t4 * 16 + l15];
        bia2[t4] = DUAL ? bias2[n0 + t4 * 16 + l15] : 0.f;
    }
#pragma unroll
    for (int mi = 0; mi < 2; ++mi) {
#pragma unroll
        for (int t4 = 0; t4 < 4; ++t4) {
            int gn = n0 + t4 * 16 + l15;
#pragma unroll
            for (int r = 0; r < 4; ++r) {
                int gm = m0 + wv * 32 + mi * 16 + quad * 4 + r;
                if (gm < M) {
                    float v = acc1[mi][t4][r] + bia1[t4];
                    C1[(size_t)gm * N + gn] = v;
                    if (OUTSPLIT) {
                        unsigned short hb = f2bfbits(v);
                        Oh[(size_t)gm * N + gn] = hb;
                        float hf = (float)__builtin_bit_cast(__bf16, hb);
                        Ol[(size_t)gm * N + gn] = f2bfbits(v - hf);
                    }
                    if (DUAL) {
                        float v2 = acc2[mi][t4][r] + bia2[t4];
                        C2[(size_t)gm * N + gn] = v2;
                    }
                }
            }
        }
    }
}

// ---------------- GATv2 aggregation: one wave per node, online softmax ----------------
// lane l covers feature dims l*4..l*4+3 ; head = l>>3 ; head-local dims (l&7)*4..
// Also emits bf16 hi/lo split of the new h for the next layer's MFMA GEMM.
__global__ __launch_bounds__(256) void gat_agg_kernel(
    const float* __restrict__ fs, const float* __restrict__ fd,
    float* __restrict__ h, const int* __restrict__ offs,
    const int* __restrict__ csr_src, const float* __restrict__ attn_l,
    unsigned short* __restrict__ h_hi, unsigned short* __restrict__ h_lo) {
    int gw = (blockIdx.x * blockDim.x + threadIdx.x) >> 6;
    if (gw >= N_NODES) return;
    int lane = threadIdx.x & 63;
    int node = gw;

    int abase = (lane >> 3) * DH + (lane & 7) * 4;
    float4 av = *(const float4*)(attn_l + abase);
    float a0 = av.x, a1 = av.y, a2 = av.z, a3 = av.w;

    float4 fdv = *(const float4*)(fd + (size_t)node * HID + lane * 4);

    int beg = offs[node], end = offs[node + 1];
    float m = -INFINITY, ssum = 0.f;
    float acc0 = 0.f, acc1 = 0.f, acc2 = 0.f, acc3 = 0.f;

    for (int idx = beg; idx < end; ++idx) {
        int sv = csr_src[idx];
        float4 fsv = *(const float4*)(fs + (size_t)sv * HID + lane * 4);
        float e0 = fsv.x + fdv.x; e0 = e0 > 0.f ? e0 : SLOPE * e0;
        float e1 = fsv.y + fdv.y; e1 = e1 > 0.f ? e1 : SLOPE * e1;
        float e2 = fsv.z + fdv.z; e2 = e2 > 0.f ? e2 : SLOPE * e2;
        float e3 = fsv.w + fdv.w; e3 = e3 > 0.f ? e3 : SLOPE * e3;
        float p = e0 * a0 + e1 * a1 + e2 * a2 + e3 * a3;
        p += __shfl_xor(p, 1, 64);
        p += __shfl_xor(p, 2, 64);
        p += __shfl_xor(p, 4, 64);
        float mn = fmaxf(m, p);
        float corr = __expf(m - mn);   // m=-inf first iter -> corr=0
        float w = __expf(p - mn);
        ssum = ssum * corr + w;
        acc0 = acc0 * corr + w * fsv.x;
        acc1 = acc1 * corr + w * fsv.y;
        acc2 = acc2 * corr + w * fsv.z;
        acc3 = acc3 * corr + w * fsv.w;
        m = mn;
    }

    float inv = ssum > 0.f ? 1.f / ssum : 0.f;
    float4 hv = *(const float4*)(h + (size_t)node * HID + lane * 4);
    float4 o;
    o.x = fmaxf(acc0 * inv + hv.x, 0.f);
    o.y = fmaxf(acc1 * inv + hv.y, 0.f);
    o.z = fmaxf(acc2 * inv + hv.z, 0.f);
    o.w = fmaxf(acc3 * inv + hv.w, 0.f);
    *(float4*)(h + (size_t)node * HID + lane * 4) = o;

    ushort4 uh, ul;
    uh.x = f2bfbits(o.x); ul.x = f2bfbits(o.x - bfhival(o.x));
    uh.y = f2bfbits(o.y); ul.y = f2bfbits(o.y - bfhival(o.y));
    uh.z = f2bfbits(o.z); ul.z = f2bfbits(o.z - bfhival(o.z));
    uh.w = f2bfbits(o.w); ul.w = f2bfbits(o.w - bfhival(o.w));
    *(ushort4*)(h_hi + (size_t)node * HID + lane * 4) = uh;
    *(ushort4*)(h_lo + (size_t)node * HID + lane * 4) = ul;
}

// ---------------- graph sum-pool (graph_ids sorted -> run-length local acc) ----------------
#define POOL_CHUNK 32
__global__ __launch_bounds__(64) void pool_kernel(const float* __restrict__ h,
                                                  const int* __restrict__ gid,
                                                  float* __restrict__ hg) {
    int t = threadIdx.x;
    int n0 = blockIdx.x * POOL_CHUNK;
    int n1 = n0 + POOL_CHUNK; if (n1 > N_NODES) n1 = N_NODES;
    if (n0 >= N_NODES) return;
    float4 acc = make_float4(0.f, 0.f, 0.f, 0.f);
    int cur = gid[n0];
    for (int n = n0; n < n1; ++n) {
        int g = gid[n];
        if (g != cur) {
            atomicAdd(&hg[(size_t)cur * HID + t * 4 + 0], acc.x);
            atomicAdd(&hg[(size_t)cur * HID + t * 4 + 1], acc.y);
            atomicAdd(&hg[(size_t)cur * HID + t * 4 + 2], acc.z);
            atomicAdd(&hg[(size_t)cur * HID + t * 4 + 3], acc.w);
            acc = make_float4(0.f, 0.f, 0.f, 0.f);
            cur = g;
        }
        float4 v = *(const float4*)(h + (size_t)n * HID + t * 4);
        acc.x += v.x; acc.y += v.y; acc.z += v.z; acc.w += v.w;
    }
    atomicAdd(&hg[(size_t)cur * HID + t * 4 + 0], acc.x);
    atomicAdd(&hg[(size_t)cur * HID + t * 4 + 1], acc.y);
    atomicAdd(&hg[(size_t)cur * HID + t * 4 + 2], acc.z);
    atomicAdd(&hg[(size_t)cur * HID + t * 4 + 3], acc.w);
}

// ---------------- classifier: one block per graph ----------------
__global__ __launch_bounds__(256) void classifier_kernel(
    const float* __restrict__ hg,
    const float* __restrict__ Wc1, const float* __restrict__ bc1,
    const float* __restrict__ Wc2, const float* __restrict__ bc2,
    const float* __restrict__ Wc3, const float* __restrict__ bc3,
    float* __restrict__ out) {
    __shared__ float xin[HID];
    __shared__ float x1[HID];
    __shared__ float x2[HID / 2];
    int g = blockIdx.x, t = threadIdx.x;
    xin[t] = hg[(size_t)g * HID + t];
    __syncthreads();
    {
        float acc = bc1[t];
        for (int k = 0; k < HID; ++k) acc += xin[k] * Wc1[k * HID + t];
        x1[t] = fmaxf(acc, 0.f);
    }
    __syncthreads();
    if (t < HID / 2) {
        float acc = bc2[t];
        for (int k = 0; k < HID; ++k) acc += x1[k] * Wc2[k * (HID / 2) + t];
        x2[t] = fmaxf(acc, 0.f);
    }
    __syncthreads();
    if (t < OUT_DIM) {
        float acc = bc3[t];
        for (int k = 0; k < HID / 2; ++k) acc += x2[k] * Wc3[k * OUT_DIM + t];
        out[g * OUT_DIM + t] = acc;
    }
}

// ---------------- launch ----------------
extern "C" void kernel_launch(void* const* d_in, const int* in_sizes, int n_in,
                              void* d_out, int out_size, void* d_ws, size_t ws_size,
                              hipStream_t stream) {
    const float* feature = (const float*)d_in[0];
    const float* W_in   = (const float*)d_in[1];
    const float* b_in   = (const float*)d_in[2];
    const float* W_src  = (const float*)d_in[3];
    const float* b_src  = (const float*)d_in[4];
    const float* W_dst  = (const float*)d_in[5];
    const float* b_dst  = (const float*)d_in[6];
    const float* attn   = (const float*)d_in[7];
    const float* Wc1    = (const float*)d_in[8];
    const float* bc1    = (const float*)d_in[9];
    const float* Wc2    = (const float*)d_in[10];
    const float* bc2    = (const float*)d_in[11];
    const float* Wc3    = (const float*)d_in[12];
    const float* bc3    = (const float*)d_in[13];
    const int* src     = (const int*)d_in[14];
    const int* dst     = (const int*)d_in[15];
    const int* gid     = (const int*)d_in[16];
    float* out = (float*)d_out;

    char* w = (char*)d_ws;
    auto alloc = [&](size_t bytes) -> void* {
        void* p = (void*)w;
        w += (bytes + 255) & ~(size_t)255;
        return p;
    };
    float* h     = (float*)alloc((size_t)N_NODES * HID * 4);
    float* fs    = (float*)alloc((size_t)N_NODES * HID * 4);
    float* fd    = (float*)alloc((size_t)N_NODES * HID * 4);
    float* hg    = (float*)alloc((size_t)NUM_GRAPHS * HID * 4);
    int* cnt     = (int*)alloc((size_t)N_NODES * 4);
    int* offs    = (int*)alloc((size_t)(N_NODES + 1) * 4);
    int* cursor  = (int*)alloc((size_t)N_NODES * 4);
    int* csr_src = (int*)alloc((size_t)N_EDGES * 4);
    unsigned short* h_hi = (unsigned short*)alloc((size_t)N_NODES * HID * 2);
    unsigned short* h_lo = (unsigned short*)alloc((size_t)N_NODES * HID * 2);
    unsigned short* WinT = (unsigned short*)alloc((size_t)IN_DIM * HID * 2);
    unsigned short* WT   = (unsigned short*)alloc((size_t)6 * HID * HID * 2);  // [3 src + 3 dst][n][k]
    // feature bf16 cast aliases fs (fs first written after in-proj GEMM finishes)
    unsigned short* featH = (unsigned short*)fs;

    // init
    hipLaunchKernelGGL(zero_kernel, dim3((N_NODES + 255) / 256), dim3(256), 0, stream,
                       (float*)cnt, N_NODES);
    hipLaunchKernelGGL(zero_kernel, dim3((NUM_GRAPHS * HID + 255) / 256), dim3(256), 0, stream,
                       hg, NUM_GRAPHS * HID);

    // casts / transposes
    hipLaunchKernelGGL(cast4_kernel, dim3((N_NODES * IN_DIM / 4 + 255) / 256), dim3(256), 0, stream,
                       feature, featH, N_NODES * IN_DIM / 4);
    hipLaunchKernelGGL(wtransK_kernel, dim3((IN_DIM * HID + 255) / 256), dim3(256), 0, stream,
                       W_in, WinT, IN_DIM, HID);
    hipLaunchKernelGGL(wtrans6_kernel, dim3((6 * 65536 + 255) / 256), dim3(256), 0, stream,
                       W_src, W_dst, WT);

    // CSR build by dst
    hipLaunchKernelGGL(count_kernel, dim3((N_EDGES + 255) / 256), dim3(256), 0, stream, dst, cnt);
    hipLaunchKernelGGL(scan_kernel, dim3(1), dim3(256), 0, stream, cnt, offs, cursor);
    hipLaunchKernelGGL(fill_kernel, dim3((N_EDGES + 255) / 256), dim3(256), 0, stream,
                       src, dst, cursor, csr_src);

    dim3 ggrid((N_NODES + 127) / 128, HID / 64);  // 157 x 4

    // input projection: h = feature @ W_in + b_in (bf16-exact inputs -> exact)
    hipLaunchKernelGGL((mfma_gemm<0, 0, 1>), ggrid, dim3(256), 0, stream,
                       featH, (const unsigned short*)nullptr,
                       WinT, b_in, h,
                       (const unsigned short*)nullptr, (const float*)nullptr, (float*)nullptr,
                       h_hi, h_lo,
                       N_NODES, IN_DIM, HID);

    // GATv2 layers
    for (int l = 0; l < LAYERS; ++l) {
        hipLaunchKernelGGL((mfma_gemm<1, 1, 0>), ggrid, dim3(256), 0, stream,
                           h_hi, h_lo,
                           WT + (size_t)l * HID * HID, b_src + (size_t)l * HID, fs,
                           WT + (size_t)(3 + l) * HID * HID, b_dst + (size_t)l * HID, fd,
                           (unsigned short*)nullptr, (unsigned short*)nullptr,
                           N_NODES, HID, HID);
        hipLaunchKernelGGL(gat_agg_kernel, dim3((N_NODES * 64 + 255) / 256), dim3(256), 0, stream,
                           fs, fd, h, offs, csr_src, attn + (size_t)l * HEADS * DH,
                           h_hi, h_lo);
    }

    // pool + classifier
    hipLaunchKernelGGL(pool_kernel, dim3((N_NODES + POOL_CHUNK - 1) / POOL_CHUNK), dim3(64), 0, stream,
                       h, gid, hg);
    hipLaunchKernelGGL(classifier_kernel, dim3(NUM_GRAPHS), dim3(256), 0, stream,
                       hg, Wc1, bc1, Wc2, bc2, Wc3, bc3, out);
}

// Round 5
// 416.583 us; speedup vs baseline: 1.9779x; 1.1733x over previous
//
#include <hip/hip_runtime.h>
#include <hip/hip_bf16.h>
#include <math.h>

#define N_NODES 20000
#define N_EDGES 320000
#define IN_DIM 128
#define HID 256
#define HEADS 8
#define DH 32
#define LAYERS 3
#define NUM_GRAPHS 64
#define OUT_DIM 10
#define SLOPE 0.2f

typedef __bf16 bf16x8 __attribute__((ext_vector_type(8)));
typedef float f32x4 __attribute__((ext_vector_type(4)));

static __device__ __forceinline__ unsigned short f2bfbits(float v) {
    __bf16 b = (__bf16)v;
    return __builtin_bit_cast(unsigned short, b);
}
static __device__ __forceinline__ float bfhival(float v) {
    __bf16 b = (__bf16)v;
    return (float)b;
}
// unpack 8 bf16 (in a uint4) -> 8 fp32, exact
static __device__ __forceinline__ void unpack8(uint4 u, float* f) {
    unsigned p0 = u.x, p1 = u.y, p2 = u.z, p3 = u.w;
    f[0] = __builtin_bit_cast(float, p0 << 16);
    f[1] = __builtin_bit_cast(float, p0 & 0xffff0000u);
    f[2] = __builtin_bit_cast(float, p1 << 16);
    f[3] = __builtin_bit_cast(float, p1 & 0xffff0000u);
    f[4] = __builtin_bit_cast(float, p2 << 16);
    f[5] = __builtin_bit_cast(float, p2 & 0xffff0000u);
    f[6] = __builtin_bit_cast(float, p3 << 16);
    f[7] = __builtin_bit_cast(float, p3 & 0xffff0000u);
}

// ---------------- utility kernels ----------------
__global__ void zero_kernel(float* __restrict__ p, int n) {
    int i = blockIdx.x * blockDim.x + threadIdx.x;
    if (i < n) p[i] = 0.f;
}

// feature fp32 (bf16-exact values) -> bf16 bits, 4 at a time
__global__ void cast4_kernel(const float* __restrict__ in, unsigned short* __restrict__ out, int n4) {
    int i = blockIdx.x * blockDim.x + threadIdx.x;
    if (i < n4) {
        float4 v = ((const float4*)in)[i];
        ushort4 o;
        o.x = f2bfbits(v.x); o.y = f2bfbits(v.y);
        o.z = f2bfbits(v.z); o.w = f2bfbits(v.w);
        ((ushort4*)out)[i] = o;
    }
}

// W_in [K=128][N=256] fp32 -> WinT [N][K] bf16 bits
__global__ void wtransK_kernel(const float* __restrict__ in, unsigned short* __restrict__ out,
                               int K, int N) {
    int idx = blockIdx.x * blockDim.x + threadIdx.x;
    if (idx < K * N) {
        int n = idx / K, k = idx % K;
        out[idx] = f2bfbits(in[k * N + n]);
    }
}

// 6 matrices (3 x W_src, 3 x W_dst), each [256][256] -> out [mat][n][k] bf16 bits
__global__ void wtrans6_kernel(const float* __restrict__ Wsrc, const float* __restrict__ Wdst,
                               unsigned short* __restrict__ out) {
    int idx = blockIdx.x * blockDim.x + threadIdx.x;
    if (idx < 6 * 65536) {
        int mat = idx >> 16;
        int r = idx & 65535;
        int n = r >> 8, k = r & 255;
        const float* base = (mat < 3) ? (Wsrc + (size_t)mat * 65536)
                                      : (Wdst + (size_t)(mat - 3) * 65536);
        out[idx] = f2bfbits(base[k * 256 + n]);
    }
}

// ---------------- CSR build (group edges by dst) ----------------
__global__ void count_kernel(const int* __restrict__ dst, int* __restrict__ cnt) {
    int e = blockIdx.x * blockDim.x + threadIdx.x;
    if (e < N_EDGES) atomicAdd(&cnt[dst[e]], 1);
}

__global__ __launch_bounds__(256) void scan_kernel(const int* __restrict__ cnt,
                                                   int* __restrict__ offs,
                                                   int* __restrict__ cursor) {
    __shared__ int part[256];
    int t = threadIdx.x;
    const int chunk = (N_NODES + 255) / 256;  // 79
    int beg = t * chunk;
    int end = beg + chunk; if (end > N_NODES) end = N_NODES;
    int s = 0;
    for (int i = beg; i < end; ++i) s += cnt[i];
    part[t] = s;
    __syncthreads();
    if (t == 0) {
        int run = 0;
        for (int i = 0; i < 256; ++i) { int v = part[i]; part[i] = run; run += v; }
        offs[N_NODES] = run;
    }
    __syncthreads();
    int run = part[t];
    for (int i = beg; i < end; ++i) {
        offs[i] = run; cursor[i] = run; run += cnt[i];
    }
}

__global__ void fill_kernel(const int* __restrict__ src, const int* __restrict__ dst,
                            int* __restrict__ cursor, int* __restrict__ csr_src) {
    int e = blockIdx.x * blockDim.x + threadIdx.x;
    if (e < N_EDGES) {
        int p = atomicAdd(&cursor[dst[e]], 1);
        csr_src[p] = src[e];
    }
}

// ---------------- MFMA GEMM ----------------
// C = (A_hi [+ A_lo])[M,K] @ B[K,N] + bias, B given TRANSPOSED as BT[n][k] bf16.
// DUAL: second B/bias sharing A.
// OUTMODE 1 (in-proj): write C1f fp32 + O1a/O1b = bf16 hi/lo split of C1.
// OUTMODE 2 (dual layer): write O1a = bf16(C1), O2 = bf16(C2). No fp32 writes.
// Block tile 128(M) x 64(N), 4 waves. mfma_f32_16x16x32_bf16 layouts per
// learn_hip m89/m91. LDS rows padded to 40 bf16 -> conflict-free ds_read_b128.
template <int SPLITA, int DUAL, int OUTMODE>
__global__ __launch_bounds__(256) void mfma_gemm(
    const unsigned short* __restrict__ Ah, const unsigned short* __restrict__ Al,
    const unsigned short* __restrict__ BT1, const float* __restrict__ bias1,
    float* __restrict__ C1f,
    unsigned short* __restrict__ O1a, unsigned short* __restrict__ O1b,
    const unsigned short* __restrict__ BT2, const float* __restrict__ bias2,
    unsigned short* __restrict__ O2,
    int M, int K, int N) {
    __shared__ unsigned short As_hi[128 * 40];
    __shared__ unsigned short As_lo[SPLITA ? 128 * 40 : 8];
    __shared__ unsigned short Bs1[64 * 40];
    __shared__ unsigned short Bs2[DUAL ? 64 * 40 : 8];

    const int t = threadIdx.x;
    const int wv = t >> 6, lane = t & 63, quad = lane >> 4, l15 = lane & 15;
    const int m0 = blockIdx.x * 128, n0 = blockIdx.y * 64;

    f32x4 zero = {0.f, 0.f, 0.f, 0.f};
    f32x4 acc1[2][4], acc2[2][4];
#pragma unroll
    for (int mi = 0; mi < 2; ++mi)
#pragma unroll
        for (int t4 = 0; t4 < 4; ++t4) { acc1[mi][t4] = zero; acc2[mi][t4] = zero; }

    for (int k0 = 0; k0 < K; k0 += 32) {
        __syncthreads();
        // stage A tiles: 128 rows x 32 k, 16B per thread x2
#pragma unroll
        for (int i = 0; i < 2; ++i) {
            int g = t + i * 256;
            int r = g >> 2, s = g & 3;
            int gm = m0 + r;
            uint4 v = make_uint4(0u, 0u, 0u, 0u);
            if (gm < M) v = *(const uint4*)(Ah + (size_t)gm * K + k0 + s * 8);
            *(uint4*)(As_hi + r * 40 + s * 8) = v;
            if (SPLITA) {
                uint4 v2 = make_uint4(0u, 0u, 0u, 0u);
                if (gm < M) v2 = *(const uint4*)(Al + (size_t)gm * K + k0 + s * 8);
                *(uint4*)(As_lo + r * 40 + s * 8) = v2;
            }
        }
        // stage B tiles: 64 n-rows x 32 k from BT[n][k]
        {
            int r = t >> 2, s = t & 3;
            int gn = n0 + r;
            *(uint4*)(Bs1 + r * 40 + s * 8) = *(const uint4*)(BT1 + (size_t)gn * K + k0 + s * 8);
            if (DUAL)
                *(uint4*)(Bs2 + r * 40 + s * 8) = *(const uint4*)(BT2 + (size_t)gn * K + k0 + s * 8);
        }
        __syncthreads();

        bf16x8 aHi[2], aLo[2];
#pragma unroll
        for (int mi = 0; mi < 2; ++mi) {
            int row = wv * 32 + mi * 16 + l15;
            aHi[mi] = __builtin_bit_cast(bf16x8, *(const uint4*)(As_hi + row * 40 + quad * 8));
            if (SPLITA)
                aLo[mi] = __builtin_bit_cast(bf16x8, *(const uint4*)(As_lo + row * 40 + quad * 8));
        }
#pragma unroll
        for (int t4 = 0; t4 < 4; ++t4) {
            int brow = t4 * 16 + l15;
            bf16x8 b1 = __builtin_bit_cast(bf16x8, *(const uint4*)(Bs1 + brow * 40 + quad * 8));
#pragma unroll
            for (int mi = 0; mi < 2; ++mi) {
                acc1[mi][t4] = __builtin_amdgcn_mfma_f32_16x16x32_bf16(aHi[mi], b1, acc1[mi][t4], 0, 0, 0);
                if (SPLITA)
                    acc1[mi][t4] = __builtin_amdgcn_mfma_f32_16x16x32_bf16(aLo[mi], b1, acc1[mi][t4], 0, 0, 0);
            }
            if (DUAL) {
                bf16x8 b2 = __builtin_bit_cast(bf16x8, *(const uint4*)(Bs2 + brow * 40 + quad * 8));
#pragma unroll
                for (int mi = 0; mi < 2; ++mi) {
                    acc2[mi][t4] = __builtin_amdgcn_mfma_f32_16x16x32_bf16(aHi[mi], b2, acc2[mi][t4], 0, 0, 0);
                    if (SPLITA)
                        acc2[mi][t4] = __builtin_amdgcn_mfma_f32_16x16x32_bf16(aLo[mi], b2, acc2[mi][t4], 0, 0, 0);
                }
            }
        }
    }

    // epilogue
    float bia1[4], bia2[4];
#pragma unroll
    for (int t4 = 0; t4 < 4; ++t4) {
        bia1[t4] = bias1[n0 + t4 * 16 + l15];
        bia2[t4] = DUAL ? bias2[n0 + t4 * 16 + l15] : 0.f;
    }
#pragma unroll
    for (int mi = 0; mi < 2; ++mi) {
#pragma unroll
        for (int t4 = 0; t4 < 4; ++t4) {
            int gn = n0 + t4 * 16 + l15;
#pragma unroll
            for (int r = 0; r < 4; ++r) {
                int gm = m0 + wv * 32 + mi * 16 + quad * 4 + r;
                if (gm < M) {
                    float v = acc1[mi][t4][r] + bia1[t4];
                    if (OUTMODE == 1) {
                        C1f[(size_t)gm * N + gn] = v;
                        unsigned short hb = f2bfbits(v);
                        O1a[(size_t)gm * N + gn] = hb;
                        float hf = (float)__builtin_bit_cast(__bf16, hb);
                        O1b[(size_t)gm * N + gn] = f2bfbits(v - hf);
                    } else {  // OUTMODE 2
                        O1a[(size_t)gm * N + gn] = f2bfbits(v);
                        float v2 = acc2[mi][t4][r] + bia2[t4];
                        O2[(size_t)gm * N + gn] = f2bfbits(v2);
                    }
                }
            }
        }
    }
}

// ---------------- GATv2 aggregation v2 ----------------
// bf16 fs/fd tables; one HALF-wave (32 lanes) per node, lane covers 8 dims via
// one uint4 (8 bf16) load per edge; head = 4 lanes; edge loop unrolled x2.
__global__ __launch_bounds__(256) void gat_agg2(
    const unsigned short* __restrict__ fsb, const unsigned short* __restrict__ fdb,
    float* __restrict__ h, const int* __restrict__ offs,
    const int* __restrict__ csr_src, const float* __restrict__ attn_l,
    unsigned short* __restrict__ h_hi, unsigned short* __restrict__ h_lo,
    int write_split) {
    int node = (blockIdx.x * blockDim.x + threadIdx.x) >> 5;
    if (node >= N_NODES) return;
    int l32 = threadIdx.x & 31;
    int dbase = l32 * 8;                           // 8 contiguous dims per lane
    int abase = (l32 >> 2) * DH + (l32 & 3) * 8;   // head = l32>>2 (4 lanes/head)

    float a[8];
#pragma unroll
    for (int j = 0; j < 8; ++j) a[j] = attn_l[abase + j];

    float fdv[8];
    unpack8(*(const uint4*)(fdb + (size_t)node * HID + dbase), fdv);

    float m = -INFINITY, ssum = 0.f;
    float acc[8];
#pragma unroll
    for (int j = 0; j < 8; ++j) acc[j] = 0.f;

    auto procU = [&](uint4 u) {
        float fsv[8];
        unpack8(u, fsv);
        float p = 0.f;
#pragma unroll
        for (int j = 0; j < 8; ++j) {
            float e = fsv[j] + fdv[j];
            e = e > 0.f ? e : SLOPE * e;
            p += e * a[j];
        }
        p += __shfl_xor(p, 1, 64);   // reduce over the 4 lanes of this head
        p += __shfl_xor(p, 2, 64);
        float mn = fmaxf(m, p);
        float corr = __expf(m - mn);  // m=-inf first edge -> corr=0
        float w = __expf(p - mn);
        ssum = ssum * corr + w;
#pragma unroll
        for (int j = 0; j < 8; ++j) acc[j] = acc[j] * corr + w * fsv[j];
        m = mn;
    };

    int beg = offs[node], end = offs[node + 1];
    int idx = beg;
    for (; idx + 2 <= end; idx += 2) {
        int sv0 = csr_src[idx];
        int sv1 = csr_src[idx + 1];
        uint4 u0 = *(const uint4*)(fsb + (size_t)sv0 * HID + dbase);
        uint4 u1 = *(const uint4*)(fsb + (size_t)sv1 * HID + dbase);
        procU(u0);
        procU(u1);
    }
    if (idx < end) {
        int sv = csr_src[idx];
        procU(*(const uint4*)(fsb + (size_t)sv * HID + dbase));
    }

    float inv = ssum > 0.f ? 1.f / ssum : 0.f;
    float4 hv0 = *(const float4*)(h + (size_t)node * HID + dbase);
    float4 hv1 = *(const float4*)(h + (size_t)node * HID + dbase + 4);
    float o[8];
    o[0] = fmaxf(acc[0] * inv + hv0.x, 0.f);
    o[1] = fmaxf(acc[1] * inv + hv0.y, 0.f);
    o[2] = fmaxf(acc[2] * inv + hv0.z, 0.f);
    o[3] = fmaxf(acc[3] * inv + hv0.w, 0.f);
    o[4] = fmaxf(acc[4] * inv + hv1.x, 0.f);
    o[5] = fmaxf(acc[5] * inv + hv1.y, 0.f);
    o[6] = fmaxf(acc[6] * inv + hv1.z, 0.f);
    o[7] = fmaxf(acc[7] * inv + hv1.w, 0.f);
    *(float4*)(h + (size_t)node * HID + dbase) = make_float4(o[0], o[1], o[2], o[3]);
    *(float4*)(h + (size_t)node * HID + dbase + 4) = make_float4(o[4], o[5], o[6], o[7]);

    if (write_split) {
        unsigned short hb[8], lb[8];
#pragma unroll
        for (int j = 0; j < 8; ++j) {
            hb[j] = f2bfbits(o[j]);
            float hf = (float)__builtin_bit_cast(__bf16, hb[j]);
            lb[j] = f2bfbits(o[j] - hf);
        }
        *(uint4*)(h_hi + (size_t)node * HID + dbase) = *(uint4*)hb;
        *(uint4*)(h_lo + (size_t)node * HID + dbase) = *(uint4*)lb;
    }
}

// ---------------- graph sum-pool (graph_ids sorted -> run-length local acc) ----------------
#define POOL_CHUNK 32
__global__ __launch_bounds__(64) void pool_kernel(const float* __restrict__ h,
                                                  const int* __restrict__ gid,
                                                  float* __restrict__ hg) {
    int t = threadIdx.x;
    int n0 = blockIdx.x * POOL_CHUNK;
    int n1 = n0 + POOL_CHUNK; if (n1 > N_NODES) n1 = N_NODES;
    if (n0 >= N_NODES) return;
    float4 acc = make_float4(0.f, 0.f, 0.f, 0.f);
    int cur = gid[n0];
    for (int n = n0; n < n1; ++n) {
        int g = gid[n];
        if (g != cur) {
            atomicAdd(&hg[(size_t)cur * HID + t * 4 + 0], acc.x);
            atomicAdd(&hg[(size_t)cur * HID + t * 4 + 1], acc.y);
            atomicAdd(&hg[(size_t)cur * HID + t * 4 + 2], acc.z);
            atomicAdd(&hg[(size_t)cur * HID + t * 4 + 3], acc.w);
            acc = make_float4(0.f, 0.f, 0.f, 0.f);
            cur = g;
        }
        float4 v = *(const float4*)(h + (size_t)n * HID + t * 4);
        acc.x += v.x; acc.y += v.y; acc.z += v.z; acc.w += v.w;
    }
    atomicAdd(&hg[(size_t)cur * HID + t * 4 + 0], acc.x);
    atomicAdd(&hg[(size_t)cur * HID + t * 4 + 1], acc.y);
    atomicAdd(&hg[(size_t)cur * HID + t * 4 + 2], acc.z);
    atomicAdd(&hg[(size_t)cur * HID + t * 4 + 3], acc.w);
}

// ---------------- classifier: one block per graph ----------------
__global__ __launch_bounds__(256) void classifier_kernel(
    const float* __restrict__ hg,
    const float* __restrict__ Wc1, const float* __restrict__ bc1,
    const float* __restrict__ Wc2, const float* __restrict__ bc2,
    const float* __restrict__ Wc3, const float* __restrict__ bc3,
    float* __restrict__ out) {
    __shared__ float xin[HID];
    __shared__ float x1[HID];
    __shared__ float x2[HID / 2];
    int g = blockIdx.x, t = threadIdx.x;
    xin[t] = hg[(size_t)g * HID + t];
    __syncthreads();
    {
        float acc = bc1[t];
        for (int k = 0; k < HID; ++k) acc += xin[k] * Wc1[k * HID + t];
        x1[t] = fmaxf(acc, 0.f);
    }
    __syncthreads();
    if (t < HID / 2) {
        float acc = bc2[t];
        for (int k = 0; k < HID; ++k) acc += x1[k] * Wc2[k * (HID / 2) + t];
        x2[t] = fmaxf(acc, 0.f);
    }
    __syncthreads();
    if (t < OUT_DIM) {
        float acc = bc3[t];
        for (int k = 0; k < HID / 2; ++k) acc += x2[k] * Wc3[k * OUT_DIM + t];
        out[g * OUT_DIM + t] = acc;
    }
}

// ---------------- launch ----------------
extern "C" void kernel_launch(void* const* d_in, const int* in_sizes, int n_in,
                              void* d_out, int out_size, void* d_ws, size_t ws_size,
                              hipStream_t stream) {
    const float* feature = (const float*)d_in[0];
    const float* W_in   = (const float*)d_in[1];
    const float* b_in   = (const float*)d_in[2];
    const float* W_src  = (const float*)d_in[3];
    const float* b_src  = (const float*)d_in[4];
    const float* W_dst  = (const float*)d_in[5];
    const float* b_dst  = (const float*)d_in[6];
    const float* attn   = (const float*)d_in[7];
    const float* Wc1    = (const float*)d_in[8];
    const float* bc1    = (const float*)d_in[9];
    const float* Wc2    = (const float*)d_in[10];
    const float* bc2    = (const float*)d_in[11];
    const float* Wc3    = (const float*)d_in[12];
    const float* bc3    = (const float*)d_in[13];
    const int* src     = (const int*)d_in[14];
    const int* dst     = (const int*)d_in[15];
    const int* gid     = (const int*)d_in[16];
    float* out = (float*)d_out;

    char* w = (char*)d_ws;
    auto alloc = [&](size_t bytes) -> void* {
        void* p = (void*)w;
        w += (bytes + 255) & ~(size_t)255;
        return p;
    };
    float* h     = (float*)alloc((size_t)N_NODES * HID * 4);
    unsigned short* fsb = (unsigned short*)alloc((size_t)N_NODES * HID * 2);
    unsigned short* fdb = (unsigned short*)alloc((size_t)N_NODES * HID * 2);
    float* hg    = (float*)alloc((size_t)NUM_GRAPHS * HID * 4);
    int* cnt     = (int*)alloc((size_t)N_NODES * 4);
    int* offs    = (int*)alloc((size_t)(N_NODES + 1) * 4);
    int* cursor  = (int*)alloc((size_t)N_NODES * 4);
    int* csr_src = (int*)alloc((size_t)N_EDGES * 4);
    unsigned short* h_hi = (unsigned short*)alloc((size_t)N_NODES * HID * 2);
    unsigned short* h_lo = (unsigned short*)alloc((size_t)N_NODES * HID * 2);
    unsigned short* WinT = (unsigned short*)alloc((size_t)IN_DIM * HID * 2);
    unsigned short* WT   = (unsigned short*)alloc((size_t)6 * HID * HID * 2);  // [3 src + 3 dst][n][k]
    unsigned short* featH = (unsigned short*)alloc((size_t)N_NODES * IN_DIM * 2);

    // init
    hipLaunchKernelGGL(zero_kernel, dim3((N_NODES + 255) / 256), dim3(256), 0, stream,
                       (float*)cnt, N_NODES);
    hipLaunchKernelGGL(zero_kernel, dim3((NUM_GRAPHS * HID + 255) / 256), dim3(256), 0, stream,
                       hg, NUM_GRAPHS * HID);

    // casts / transposes
    hipLaunchKernelGGL(cast4_kernel, dim3((N_NODES * IN_DIM / 4 + 255) / 256), dim3(256), 0, stream,
                       feature, featH, N_NODES * IN_DIM / 4);
    hipLaunchKernelGGL(wtransK_kernel, dim3((IN_DIM * HID + 255) / 256), dim3(256), 0, stream,
                       W_in, WinT, IN_DIM, HID);
    hipLaunchKernelGGL(wtrans6_kernel, dim3((6 * 65536 + 255) / 256), dim3(256), 0, stream,
                       W_src, W_dst, WT);

    // CSR build by dst
    hipLaunchKernelGGL(count_kernel, dim3((N_EDGES + 255) / 256), dim3(256), 0, stream, dst, cnt);
    hipLaunchKernelGGL(scan_kernel, dim3(1), dim3(256), 0, stream, cnt, offs, cursor);
    hipLaunchKernelGGL(fill_kernel, dim3((N_EDGES + 255) / 256), dim3(256), 0, stream,
                       src, dst, cursor, csr_src);

    dim3 ggrid((N_NODES + 127) / 128, HID / 64);  // 157 x 4

    // input projection: h = feature @ W_in + b_in (bf16-exact inputs -> exact)
    hipLaunchKernelGGL((mfma_gemm<0, 0, 1>), ggrid, dim3(256), 0, stream,
                       featH, (const unsigned short*)nullptr,
                       WinT, b_in, h, h_hi, h_lo,
                       (const unsigned short*)nullptr, (const float*)nullptr,
                       (unsigned short*)nullptr,
                       N_NODES, IN_DIM, HID);

    // GATv2 layers
    for (int l = 0; l < LAYERS; ++l) {
        hipLaunchKernelGGL((mfma_gemm<1, 1, 2>), ggrid, dim3(256), 0, stream,
                           h_hi, h_lo,
                           WT + (size_t)l * HID * HID, b_src + (size_t)l * HID,
                           (float*)nullptr, fsb, (unsigned short*)nullptr,
                           WT + (size_t)(3 + l) * HID * HID, b_dst + (size_t)l * HID, fdb,
                           N_NODES, HID, HID);
        hipLaunchKernelGGL(gat_agg2, dim3((N_NODES * 32 + 255) / 256), dim3(256), 0, stream,
                           fsb, fdb, h, offs, csr_src, attn + (size_t)l * HEADS * DH,
                           h_hi, h_lo, (l < LAYERS - 1) ? 1 : 0);
    }

    // pool + classifier
    hipLaunchKernelGGL(pool_kernel, dim3((N_NODES + POOL_CHUNK - 1) / POOL_CHUNK), dim3(64), 0, stream,
                       h, gid, hg);
    hipLaunchKernelGGL(classifier_kernel, dim3(NUM_GRAPHS), dim3(256), 0, stream,
                       hg, Wc1, bc1, Wc2, bc2, Wc3, bc3, out);
}

// Round 6
// 392.191 us; speedup vs baseline: 2.1009x; 1.0622x over previous
//
#include <hip/hip_runtime.h>
#include <hip/hip_bf16.h>
#include <math.h>

#define N_NODES 20000
#define N_EDGES 320000
#define IN_DIM 128
#define HID 256
#define HEADS 8
#define DH 32
#define LAYERS 3
#define NUM_GRAPHS 64
#define OUT_DIM 10
#define SLOPE 0.2f

typedef __bf16 bf16x8 __attribute__((ext_vector_type(8)));
typedef float f32x4 __attribute__((ext_vector_type(4)));

static __device__ __forceinline__ unsigned short f2bfbits(float v) {
    __bf16 b = (__bf16)v;
    return __builtin_bit_cast(unsigned short, b);
}
static __device__ __forceinline__ float bfhival(float v) {
    __bf16 b = (__bf16)v;
    return (float)b;
}
// unpack 8 bf16 (in a uint4) -> 8 fp32, exact
static __device__ __forceinline__ void unpack8(uint4 u, float* f) {
    unsigned p0 = u.x, p1 = u.y, p2 = u.z, p3 = u.w;
    f[0] = __builtin_bit_cast(float, p0 << 16);
    f[1] = __builtin_bit_cast(float, p0 & 0xffff0000u);
    f[2] = __builtin_bit_cast(float, p1 << 16);
    f[3] = __builtin_bit_cast(float, p1 & 0xffff0000u);
    f[4] = __builtin_bit_cast(float, p2 << 16);
    f[5] = __builtin_bit_cast(float, p2 & 0xffff0000u);
    f[6] = __builtin_bit_cast(float, p3 << 16);
    f[7] = __builtin_bit_cast(float, p3 & 0xffff0000u);
}

// ---------------- utility kernels ----------------
__global__ void zero_kernel(float* __restrict__ p, int n) {
    int i = blockIdx.x * blockDim.x + threadIdx.x;
    if (i < n) p[i] = 0.f;
}

// feature fp32 (bf16-exact values) -> bf16 bits, 4 at a time
__global__ void cast4_kernel(const float* __restrict__ in, unsigned short* __restrict__ out, int n4) {
    int i = blockIdx.x * blockDim.x + threadIdx.x;
    if (i < n4) {
        float4 v = ((const float4*)in)[i];
        ushort4 o;
        o.x = f2bfbits(v.x); o.y = f2bfbits(v.y);
        o.z = f2bfbits(v.z); o.w = f2bfbits(v.w);
        ((ushort4*)out)[i] = o;
    }
}

// fused weight transpose+cast:
//   idx < 32768:  W_in [128][256] -> WinT [n][k] bf16
//   else:         6 mats (3 W_src + 3 W_dst) [256][256] -> WT [mat][n][k] bf16
#define WTRANS_TOTAL (IN_DIM * HID + 6 * HID * HID)
__global__ void wtrans_all_kernel(const float* __restrict__ Win,
                                  const float* __restrict__ Wsrc,
                                  const float* __restrict__ Wdst,
                                  unsigned short* __restrict__ WinT,
                                  unsigned short* __restrict__ WT) {
    int idx = blockIdx.x * blockDim.x + threadIdx.x;
    if (idx < IN_DIM * HID) {
        int n = idx / IN_DIM, k = idx % IN_DIM;
        WinT[idx] = f2bfbits(Win[k * HID + n]);
    } else if (idx < WTRANS_TOTAL) {
        int r6 = idx - IN_DIM * HID;
        int mat = r6 >> 16;
        int r = r6 & 65535;
        int n = r >> 8, k = r & 255;
        const float* base = (mat < 3) ? (Wsrc + (size_t)mat * 65536)
                                      : (Wdst + (size_t)(mat - 3) * 65536);
        WT[r6] = f2bfbits(base[k * 256 + n]);
    }
}

// ---------------- CSR build (group edges by dst) ----------------
__global__ void count_kernel(const int* __restrict__ dst, int* __restrict__ cnt) {
    int e = blockIdx.x * blockDim.x + threadIdx.x;
    if (e < N_EDGES) atomicAdd(&cnt[dst[e]], 1);
}

// parallel single-block scan: 1024 threads x 20 counters each, register-cached,
// wave-shfl inclusive scan + wave-sum scan.
#define SCAN_CHUNK 20
__global__ __launch_bounds__(1024) void scan_kernel(const int* __restrict__ cnt,
                                                    int* __restrict__ offs,
                                                    int* __restrict__ cursor) {
    __shared__ int wsum[16];
    int t = threadIdx.x;
    int beg = t * SCAN_CHUNK;

    int c[SCAN_CHUNK];
    int s = 0;
#pragma unroll
    for (int i = 0; i < SCAN_CHUNK; ++i) {
        int idx = beg + i;
        int x = (idx < N_NODES) ? cnt[idx] : 0;
        c[i] = x; s += x;
    }

    // wave-level inclusive scan of per-thread sums
    int v = s;
#pragma unroll
    for (int d = 1; d < 64; d <<= 1) {
        int u = __shfl_up(v, d, 64);
        if ((t & 63) >= d) v += u;
    }
    if ((t & 63) == 63) wsum[t >> 6] = v;
    __syncthreads();
    if (t < 16) {
        int wv = wsum[t];
#pragma unroll
        for (int d = 1; d < 16; d <<= 1) {
            int u = __shfl_up(wv, d, 64);
            if (t >= d) wv += u;
        }
        wsum[t] = wv;  // inclusive wave-sum scan
    }
    __syncthreads();
    int waveoff = (t >> 6) ? wsum[(t >> 6) - 1] : 0;
    int run = waveoff + v - s;  // exclusive prefix for this thread's chunk
#pragma unroll
    for (int i = 0; i < SCAN_CHUNK; ++i) {
        int idx = beg + i;
        if (idx < N_NODES) { offs[idx] = run; cursor[idx] = run; }
        run += c[i];
    }
    if (t == 0) offs[N_NODES] = wsum[15];
}

__global__ void fill_kernel(const int* __restrict__ src, const int* __restrict__ dst,
                            int* __restrict__ cursor, int* __restrict__ csr_src) {
    int e = blockIdx.x * blockDim.x + threadIdx.x;
    if (e < N_EDGES) {
        int p = atomicAdd(&cursor[dst[e]], 1);
        csr_src[p] = src[e];
    }
}

// ---------------- MFMA GEMM ----------------
// C = (A_hi [+ A_lo])[M,K] @ B[K,N] + bias, B given TRANSPOSED as BT[n][k] bf16.
// DUAL: second B/bias sharing A.
// OUTMODE 1 (in-proj): write C1f fp32 + O1a/O1b = bf16 hi/lo split of C1.
// OUTMODE 2 (dual layer): write O1a = bf16(C1), O2 = bf16(C2). No fp32 writes.
// Block tile 128(M) x 64(N), 4 waves. mfma_f32_16x16x32_bf16 layouts per
// learn_hip m89/m91. LDS rows padded to 40 bf16 -> conflict-free ds_read_b128.
template <int SPLITA, int DUAL, int OUTMODE>
__global__ __launch_bounds__(256) void mfma_gemm(
    const unsigned short* __restrict__ Ah, const unsigned short* __restrict__ Al,
    const unsigned short* __restrict__ BT1, const float* __restrict__ bias1,
    float* __restrict__ C1f,
    unsigned short* __restrict__ O1a, unsigned short* __restrict__ O1b,
    const unsigned short* __restrict__ BT2, const float* __restrict__ bias2,
    unsigned short* __restrict__ O2,
    int M, int K, int N) {
    __shared__ unsigned short As_hi[128 * 40];
    __shared__ unsigned short As_lo[SPLITA ? 128 * 40 : 8];
    __shared__ unsigned short Bs1[64 * 40];
    __shared__ unsigned short Bs2[DUAL ? 64 * 40 : 8];

    const int t = threadIdx.x;
    const int wv = t >> 6, lane = t & 63, quad = lane >> 4, l15 = lane & 15;
    const int m0 = blockIdx.x * 128, n0 = blockIdx.y * 64;

    f32x4 zero = {0.f, 0.f, 0.f, 0.f};
    f32x4 acc1[2][4], acc2[2][4];
#pragma unroll
    for (int mi = 0; mi < 2; ++mi)
#pragma unroll
        for (int t4 = 0; t4 < 4; ++t4) { acc1[mi][t4] = zero; acc2[mi][t4] = zero; }

    for (int k0 = 0; k0 < K; k0 += 32) {
        __syncthreads();
        // stage A tiles: 128 rows x 32 k, 16B per thread x2
#pragma unroll
        for (int i = 0; i < 2; ++i) {
            int g = t + i * 256;
            int r = g >> 2, s = g & 3;
            int gm = m0 + r;
            uint4 v = make_uint4(0u, 0u, 0u, 0u);
            if (gm < M) v = *(const uint4*)(Ah + (size_t)gm * K + k0 + s * 8);
            *(uint4*)(As_hi + r * 40 + s * 8) = v;
            if (SPLITA) {
                uint4 v2 = make_uint4(0u, 0u, 0u, 0u);
                if (gm < M) v2 = *(const uint4*)(Al + (size_t)gm * K + k0 + s * 8);
                *(uint4*)(As_lo + r * 40 + s * 8) = v2;
            }
        }
        // stage B tiles: 64 n-rows x 32 k from BT[n][k]
        {
            int r = t >> 2, s = t & 3;
            int gn = n0 + r;
            *(uint4*)(Bs1 + r * 40 + s * 8) = *(const uint4*)(BT1 + (size_t)gn * K + k0 + s * 8);
            if (DUAL)
                *(uint4*)(Bs2 + r * 40 + s * 8) = *(const uint4*)(BT2 + (size_t)gn * K + k0 + s * 8);
        }
        __syncthreads();

        bf16x8 aHi[2], aLo[2];
#pragma unroll
        for (int mi = 0; mi < 2; ++mi) {
            int row = wv * 32 + mi * 16 + l15;
            aHi[mi] = __builtin_bit_cast(bf16x8, *(const uint4*)(As_hi + row * 40 + quad * 8));
            if (SPLITA)
                aLo[mi] = __builtin_bit_cast(bf16x8, *(const uint4*)(As_lo + row * 40 + quad * 8));
        }
#pragma unroll
        for (int t4 = 0; t4 < 4; ++t4) {
            int brow = t4 * 16 + l15;
            bf16x8 b1 = __builtin_bit_cast(bf16x8, *(const uint4*)(Bs1 + brow * 40 + quad * 8));
#pragma unroll
            for (int mi = 0; mi < 2; ++mi) {
                acc1[mi][t4] = __builtin_amdgcn_mfma_f32_16x16x32_bf16(aHi[mi], b1, acc1[mi][t4], 0, 0, 0);
                if (SPLITA)
                    acc1[mi][t4] = __builtin_amdgcn_mfma_f32_16x16x32_bf16(aLo[mi], b1, acc1[mi][t4], 0, 0, 0);
            }
            if (DUAL) {
                bf16x8 b2 = __builtin_bit_cast(bf16x8, *(const uint4*)(Bs2 + brow * 40 + quad * 8));
#pragma unroll
                for (int mi = 0; mi < 2; ++mi) {
                    acc2[mi][t4] = __builtin_amdgcn_mfma_f32_16x16x32_bf16(aHi[mi], b2, acc2[mi][t4], 0, 0, 0);
                    if (SPLITA)
                        acc2[mi][t4] = __builtin_amdgcn_mfma_f32_16x16x32_bf16(aLo[mi], b2, acc2[mi][t4], 0, 0, 0);
                }
            }
        }
    }

    // epilogue
    float bia1[4], bia2[4];
#pragma unroll
    for (int t4 = 0; t4 < 4; ++t4) {
        bia1[t4] = bias1[n0 + t4 * 16 + l15];
        bia2[t4] = DUAL ? bias2[n0 + t4 * 16 + l15] : 0.f;
    }
#pragma unroll
    for (int mi = 0; mi < 2; ++mi) {
#pragma unroll
        for (int t4 = 0; t4 < 4; ++t4) {
            int gn = n0 + t4 * 16 + l15;
#pragma unroll
            for (int r = 0; r < 4; ++r) {
                int gm = m0 + wv * 32 + mi * 16 + quad * 4 + r;
                if (gm < M) {
                    float v = acc1[mi][t4][r] + bia1[t4];
                    if (OUTMODE == 1) {
                        C1f[(size_t)gm * N + gn] = v;
                        unsigned short hb = f2bfbits(v);
                        O1a[(size_t)gm * N + gn] = hb;
                        float hf = (float)__builtin_bit_cast(__bf16, hb);
                        O1b[(size_t)gm * N + gn] = f2bfbits(v - hf);
                    } else {  // OUTMODE 2
                        O1a[(size_t)gm * N + gn] = f2bfbits(v);
                        float v2 = acc2[mi][t4][r] + bia2[t4];
                        O2[(size_t)gm * N + gn] = f2bfbits(v2);
                    }
                }
            }
        }
    }
}

// ---------------- GATv2 aggregation v2 ----------------
// bf16 fs/fd tables; one HALF-wave (32 lanes) per node, lane covers 8 dims via
// one uint4 (8 bf16) load per edge; head = 4 lanes; edge loop unrolled x4.
__global__ __launch_bounds__(256) void gat_agg2(
    const unsigned short* __restrict__ fsb, const unsigned short* __restrict__ fdb,
    float* __restrict__ h, const int* __restrict__ offs,
    const int* __restrict__ csr_src, const float* __restrict__ attn_l,
    unsigned short* __restrict__ h_hi, unsigned short* __restrict__ h_lo,
    int write_split) {
    int node = (blockIdx.x * blockDim.x + threadIdx.x) >> 5;
    if (node >= N_NODES) return;
    int l32 = threadIdx.x & 31;
    int dbase = l32 * 8;                           // 8 contiguous dims per lane
    int abase = (l32 >> 2) * DH + (l32 & 3) * 8;   // head = l32>>2 (4 lanes/head)

    float a[8];
#pragma unroll
    for (int j = 0; j < 8; ++j) a[j] = attn_l[abase + j];

    float fdv[8];
    unpack8(*(const uint4*)(fdb + (size_t)node * HID + dbase), fdv);

    float m = -INFINITY, ssum = 0.f;
    float acc[8];
#pragma unroll
    for (int j = 0; j < 8; ++j) acc[j] = 0.f;

    auto procU = [&](uint4 u) {
        float fsv[8];
        unpack8(u, fsv);
        float p = 0.f;
#pragma unroll
        for (int j = 0; j < 8; ++j) {
            float e = fsv[j] + fdv[j];
            e = e > 0.f ? e : SLOPE * e;
            p += e * a[j];
        }
        p += __shfl_xor(p, 1, 64);   // reduce over the 4 lanes of this head
        p += __shfl_xor(p, 2, 64);
        float mn = fmaxf(m, p);
        float corr = __expf(m - mn);  // m=-inf first edge -> corr=0
        float w = __expf(p - mn);
        ssum = ssum * corr + w;
#pragma unroll
        for (int j = 0; j < 8; ++j) acc[j] = acc[j] * corr + w * fsv[j];
        m = mn;
    };

    int beg = offs[node], end = offs[node + 1];
    int idx = beg;
    for (; idx + 4 <= end; idx += 4) {
        int sv0 = csr_src[idx];
        int sv1 = csr_src[idx + 1];
        int sv2 = csr_src[idx + 2];
        int sv3 = csr_src[idx + 3];
        uint4 u0 = *(const uint4*)(fsb + (size_t)sv0 * HID + dbase);
        uint4 u1 = *(const uint4*)(fsb + (size_t)sv1 * HID + dbase);
        uint4 u2 = *(const uint4*)(fsb + (size_t)sv2 * HID + dbase);
        uint4 u3 = *(const uint4*)(fsb + (size_t)sv3 * HID + dbase);
        procU(u0);
        procU(u1);
        procU(u2);
        procU(u3);
    }
    for (; idx < end; ++idx) {
        int sv = csr_src[idx];
        procU(*(const uint4*)(fsb + (size_t)sv * HID + dbase));
    }

    float inv = ssum > 0.f ? 1.f / ssum : 0.f;
    float4 hv0 = *(const float4*)(h + (size_t)node * HID + dbase);
    float4 hv1 = *(const float4*)(h + (size_t)node * HID + dbase + 4);
    float o[8];
    o[0] = fmaxf(acc[0] * inv + hv0.x, 0.f);
    o[1] = fmaxf(acc[1] * inv + hv0.y, 0.f);
    o[2] = fmaxf(acc[2] * inv + hv0.z, 0.f);
    o[3] = fmaxf(acc[3] * inv + hv0.w, 0.f);
    o[4] = fmaxf(acc[4] * inv + hv1.x, 0.f);
    o[5] = fmaxf(acc[5] * inv + hv1.y, 0.f);
    o[6] = fmaxf(acc[6] * inv + hv1.z, 0.f);
    o[7] = fmaxf(acc[7] * inv + hv1.w, 0.f);
    *(float4*)(h + (size_t)node * HID + dbase) = make_float4(o[0], o[1], o[2], o[3]);
    *(float4*)(h + (size_t)node * HID + dbase + 4) = make_float4(o[4], o[5], o[6], o[7]);

    if (write_split) {
        unsigned short hb[8], lb[8];
#pragma unroll
        for (int j = 0; j < 8; ++j) {
            hb[j] = f2bfbits(o[j]);
            float hf = (float)__builtin_bit_cast(__bf16, hb[j]);
            lb[j] = f2bfbits(o[j] - hf);
        }
        *(uint4*)(h_hi + (size_t)node * HID + dbase) = *(uint4*)hb;
        *(uint4*)(h_lo + (size_t)node * HID + dbase) = *(uint4*)lb;
    }
}

// ---------------- graph sum-pool (graph_ids sorted -> run-length local acc) ----------------
#define POOL_CHUNK 32
__global__ __launch_bounds__(64) void pool_kernel(const float* __restrict__ h,
                                                  const int* __restrict__ gid,
                                                  float* __restrict__ hg) {
    int t = threadIdx.x;
    int n0 = blockIdx.x * POOL_CHUNK;
    int n1 = n0 + POOL_CHUNK; if (n1 > N_NODES) n1 = N_NODES;
    if (n0 >= N_NODES) return;
    float4 acc = make_float4(0.f, 0.f, 0.f, 0.f);
    int cur = gid[n0];
    for (int n = n0; n < n1; ++n) {
        int g = gid[n];
        if (g != cur) {
            atomicAdd(&hg[(size_t)cur * HID + t * 4 + 0], acc.x);
            atomicAdd(&hg[(size_t)cur * HID + t * 4 + 1], acc.y);
            atomicAdd(&hg[(size_t)cur * HID + t * 4 + 2], acc.z);
            atomicAdd(&hg[(size_t)cur * HID + t * 4 + 3], acc.w);
            acc = make_float4(0.f, 0.f, 0.f, 0.f);
            cur = g;
        }
        float4 v = *(const float4*)(h + (size_t)n * HID + t * 4);
        acc.x += v.x; acc.y += v.y; acc.z += v.z; acc.w += v.w;
    }
    atomicAdd(&hg[(size_t)cur * HID + t * 4 + 0], acc.x);
    atomicAdd(&hg[(size_t)cur * HID + t * 4 + 1], acc.y);
    atomicAdd(&hg[(size_t)cur * HID + t * 4 + 2], acc.z);
    atomicAdd(&hg[(size_t)cur * HID + t * 4 + 3], acc.w);
}

// ---------------- classifier: one block per graph ----------------
__global__ __launch_bounds__(256) void classifier_kernel(
    const float* __restrict__ hg,
    const float* __restrict__ Wc1, const float* __restrict__ bc1,
    const float* __restrict__ Wc2, const float* __restrict__ bc2,
    const float* __restrict__ Wc3, const float* __restrict__ bc3,
    float* __restrict__ out) {
    __shared__ float xin[HID];
    __shared__ float x1[HID];
    __shared__ float x2[HID / 2];
    int g = blockIdx.x, t = threadIdx.x;
    xin[t] = hg[(size_t)g * HID + t];
    __syncthreads();
    {
        float acc = bc1[t];
        for (int k = 0; k < HID; ++k) acc += xin[k] * Wc1[k * HID + t];
        x1[t] = fmaxf(acc, 0.f);
    }
    __syncthreads();
    if (t < HID / 2) {
        float acc = bc2[t];
        for (int k = 0; k < HID; ++k) acc += x1[k] * Wc2[k * (HID / 2) + t];
        x2[t] = fmaxf(acc, 0.f);
    }
    __syncthreads();
    if (t < OUT_DIM) {
        float acc = bc3[t];
        for (int k = 0; k < HID / 2; ++k) acc += x2[k] * Wc3[k * OUT_DIM + t];
        out[g * OUT_DIM + t] = acc;
    }
}

// ---------------- launch ----------------
extern "C" void kernel_launch(void* const* d_in, const int* in_sizes, int n_in,
                              void* d_out, int out_size, void* d_ws, size_t ws_size,
                              hipStream_t stream) {
    const float* feature = (const float*)d_in[0];
    const float* W_in   = (const float*)d_in[1];
    const float* b_in   = (const float*)d_in[2];
    const float* W_src  = (const float*)d_in[3];
    const float* b_src  = (const float*)d_in[4];
    const float* W_dst  = (const float*)d_in[5];
    const float* b_dst  = (const float*)d_in[6];
    const float* attn   = (const float*)d_in[7];
    const float* Wc1    = (const float*)d_in[8];
    const float* bc1    = (const float*)d_in[9];
    const float* Wc2    = (const float*)d_in[10];
    const float* bc2    = (const float*)d_in[11];
    const float* Wc3    = (const float*)d_in[12];
    const float* bc3    = (const float*)d_in[13];
    const int* src     = (const int*)d_in[14];
    const int* dst     = (const int*)d_in[15];
    const int* gid     = (const int*)d_in[16];
    float* out = (float*)d_out;

    char* w = (char*)d_ws;
    auto alloc = [&](size_t bytes) -> void* {
        void* p = (void*)w;
        w += (bytes + 255) & ~(size_t)255;
        return p;
    };
    float* h     = (float*)alloc((size_t)N_NODES * HID * 4);
    unsigned short* fsb = (unsigned short*)alloc((size_t)N_NODES * HID * 2);
    unsigned short* fdb = (unsigned short*)alloc((size_t)N_NODES * HID * 2);
    float* hg    = (float*)alloc((size_t)NUM_GRAPHS * HID * 4);
    int* cnt     = (int*)alloc((size_t)N_NODES * 4);
    int* offs    = (int*)alloc((size_t)(N_NODES + 1) * 4);
    int* cursor  = (int*)alloc((size_t)N_NODES * 4);
    int* csr_src = (int*)alloc((size_t)N_EDGES * 4);
    unsigned short* h_hi = (unsigned short*)alloc((size_t)N_NODES * HID * 2);
    unsigned short* h_lo = (unsigned short*)alloc((size_t)N_NODES * HID * 2);
    unsigned short* WinT = (unsigned short*)alloc((size_t)IN_DIM * HID * 2);
    unsigned short* WT   = (unsigned short*)alloc((size_t)6 * HID * HID * 2);  // [3 src + 3 dst][n][k]
    unsigned short* featH = (unsigned short*)alloc((size_t)N_NODES * IN_DIM * 2);

    // init
    hipLaunchKernelGGL(zero_kernel, dim3((N_NODES + 255) / 256), dim3(256), 0, stream,
                       (float*)cnt, N_NODES);
    hipLaunchKernelGGL(zero_kernel, dim3((NUM_GRAPHS * HID + 255) / 256), dim3(256), 0, stream,
                       hg, NUM_GRAPHS * HID);

    // casts / transposes
    hipLaunchKernelGGL(cast4_kernel, dim3((N_NODES * IN_DIM / 4 + 255) / 256), dim3(256), 0, stream,
                       feature, featH, N_NODES * IN_DIM / 4);
    hipLaunchKernelGGL(wtrans_all_kernel, dim3((WTRANS_TOTAL + 255) / 256), dim3(256), 0, stream,
                       W_in, W_src, W_dst, WinT, WT);

    // CSR build by dst
    hipLaunchKernelGGL(count_kernel, dim3((N_EDGES + 255) / 256), dim3(256), 0, stream, dst, cnt);
    hipLaunchKernelGGL(scan_kernel, dim3(1), dim3(1024), 0, stream, cnt, offs, cursor);
    hipLaunchKernelGGL(fill_kernel, dim3((N_EDGES + 255) / 256), dim3(256), 0, stream,
                       src, dst, cursor, csr_src);

    dim3 ggrid((N_NODES + 127) / 128, HID / 64);  // 157 x 4

    // input projection: h = feature @ W_in + b_in (bf16-exact inputs -> exact)
    hipLaunchKernelGGL((mfma_gemm<0, 0, 1>), ggrid, dim3(256), 0, stream,
                       featH, (const unsigned short*)nullptr,
                       WinT, b_in, h, h_hi, h_lo,
                       (const unsigned short*)nullptr, (const float*)nullptr,
                       (unsigned short*)nullptr,
                       N_NODES, IN_DIM, HID);

    // GATv2 layers
    for (int l = 0; l < LAYERS; ++l) {
        hipLaunchKernelGGL((mfma_gemm<1, 1, 2>), ggrid, dim3(256), 0, stream,
                           h_hi, h_lo,
                           WT + (size_t)l * HID * HID, b_src + (size_t)l * HID,
                           (float*)nullptr, fsb, (unsigned short*)nullptr,
                           WT + (size_t)(3 + l) * HID * HID, b_dst + (size_t)l * HID, fdb,
                           N_NODES, HID, HID);
        hipLaunchKernelGGL(gat_agg2, dim3((N_NODES * 32 + 255) / 256), dim3(256), 0, stream,
                           fsb, fdb, h, offs, csr_src, attn + (size_t)l * HEADS * DH,
                           h_hi, h_lo, (l < LAYERS - 1) ? 1 : 0);
    }

    // pool + classifier
    hipLaunchKernelGGL(pool_kernel, dim3((N_NODES + POOL_CHUNK - 1) / POOL_CHUNK), dim3(64), 0, stream,
                       h, gid, hg);
    hipLaunchKernelGGL(classifier_kernel, dim3(NUM_GRAPHS), dim3(256), 0, stream,
                       hg, Wc1, bc1, Wc2, bc2, Wc3, bc3, out);
}